// Round 3
// baseline (351.533 us; speedup 1.0000x reference)
//
#include <hip/hip_runtime.h>
#include <hip/hip_bf16.h>

// Problem constants
#define BATCH 16
#define CIN 8
#define COUT 8
#define HH 512
#define WW 512
constexpr int TPX = 4;                        // pixels per thread along h
constexpr float EPS = 1e-5f;
constexpr float NPC = (float)BATCH * HH * WW; // per-channel element count

// Native vector types — required by __builtin_nontemporal_* (HIP_vector_type is rejected)
typedef unsigned int uv4 __attribute__((ext_vector_type(4)));
typedef float        fv4 __attribute__((ext_vector_type(4)));

__device__ __forceinline__ unsigned short f2bf(float f) {
    unsigned u = __float_as_uint(f);
    unsigned r = (u + 0x7fffu + ((u >> 16) & 1u)) >> 16;  // RNE
    return (unsigned short)r;
}

// MODE 0: conv -> bf16 ws + stats atomics
// MODE 1: conv -> stats atomics only
// MODE 2: conv recompute -> normalize -> fp32 out (reads stats)
template <int MODE>
__global__ __launch_bounds__(256, 2)
void conv_kernel(const float* __restrict__ x,
                 const float* __restrict__ lin_w,
                 const float* __restrict__ gamma,
                 const float* __restrict__ beta,
                 unsigned short* __restrict__ ws_y,
                 float* __restrict__ stats,
                 float* __restrict__ out) {
    const int w  = blockIdx.x * 256 + threadIdx.x;   // 0..511
    const int h0 = blockIdx.y * TPX;                  // 0..508
    const int b  = blockIdx.z;

    // Row/col geometry + padding masks: computed ONCE, reused for all 8 ic.
    int   off[6][3];
    float msk[6][3];
    {
        const int wm = max(w - 1, 0), wp = min(w + 1, WW - 1);
        const float cl = (w >= 1) ? 1.f : 0.f;
        const float cr = (w <= WW - 2) ? 1.f : 0.f;
#pragma unroll
        for (int r = 0; r < 6; ++r) {
            const int hraw = h0 - 1 + r;
            const int hcl  = min(max(hraw, 0), HH - 1);
            const float rv = (hraw >= 0 && hraw < HH) ? 1.f : 0.f;
            off[r][0] = hcl * WW + wm;
            off[r][1] = hcl * WW + w;
            off[r][2] = hcl * WW + wp;
            msk[r][0] = rv * cl;
            msk[r][1] = rv;
            msk[r][2] = rv * cr;
        }
    }

    const float* xb = x + (size_t)b * CIN * HH * WW;

    float acc[TPX][COUT];
#pragma unroll
    for (int px = 0; px < TPX; ++px)
#pragma unroll
        for (int oc = 0; oc < COUT; ++oc) acc[px][oc] = 0.f;

    // Register double-buffer: prefetch ic+1's 18 x-values while FMA-ing ic.
    float xv[2][6][3];
#pragma unroll
    for (int r = 0; r < 6; ++r)
#pragma unroll
        for (int c = 0; c < 3; ++c)
            xv[0][r][c] = xb[off[r][c]] * msk[r][c];

#pragma unroll
    for (int ic = 0; ic < CIN; ++ic) {
        const int cur = ic & 1;
        if (ic + 1 < CIN) {
            const float* xn = xb + (size_t)(ic + 1) * HH * WW;  // uniform base -> saddr loads
#pragma unroll
            for (int r = 0; r < 6; ++r)
#pragma unroll
                for (int c = 0; c < 3; ++c)
                    xv[cur ^ 1][r][c] = xn[off[r][c]] * msk[r][c];
        }
        const float* wgt = lin_w + ic * COUT * 9;  // uniform -> s_load into SGPRs
#pragma unroll
        for (int kh = 0; kh < 3; ++kh)
#pragma unroll
            for (int kw = 0; kw < 3; ++kw) {
#pragma unroll
                for (int px = 0; px < TPX; ++px) {
                    const float xval = xv[cur][kh + px][kw];
#pragma unroll
                    for (int oc = 0; oc < COUT; ++oc)
                        acc[px][oc] = fmaf(xval, wgt[oc * 9 + kh * 3 + kw], acc[px][oc]);
                }
            }
    }

    if (MODE == 0 || MODE == 1) {
        float s[COUT], q[COUT];
#pragma unroll
        for (int oc = 0; oc < COUT; ++oc) {
            float ss = 0.f, qq = 0.f;
#pragma unroll
            for (int px = 0; px < TPX; ++px) {
                ss += acc[px][oc];
                qq = fmaf(acc[px][oc], acc[px][oc], qq);
            }
            s[oc] = ss; q[oc] = qq;
        }
#pragma unroll
        for (int offd = 32; offd > 0; offd >>= 1) {
#pragma unroll
            for (int oc = 0; oc < COUT; ++oc) {
                s[oc] += __shfl_down(s[oc], offd);
                q[oc] += __shfl_down(q[oc], offd);
            }
        }
        __shared__ float reds[4][2 * COUT];
        const int lane = threadIdx.x & 63, wv = threadIdx.x >> 6;
        if (lane == 0) {
#pragma unroll
            for (int oc = 0; oc < COUT; ++oc) {
                reds[wv][oc] = s[oc];
                reds[wv][COUT + oc] = q[oc];
            }
        }
        __syncthreads();
        if (threadIdx.x < 2 * COUT) {
            float v = reds[0][threadIdx.x] + reds[1][threadIdx.x] +
                      reds[2][threadIdx.x] + reds[3][threadIdx.x];
            atomicAdd(&stats[threadIdx.x], v);
        }
        if (MODE == 0) {
#pragma unroll
            for (int oc = 0; oc < COUT; ++oc)
#pragma unroll
                for (int px = 0; px < TPX; ++px) {
                    size_t oidx = (((size_t)(b * COUT + oc)) * HH + (h0 + px)) * WW + w;
                    __builtin_nontemporal_store(f2bf(acc[px][oc]), &ws_y[oidx]);
                }
        }
    } else { // MODE 2
#pragma unroll
        for (int oc = 0; oc < COUT; ++oc) {
            const float mean = stats[oc] * (1.f / NPC);
            const float var  = stats[COUT + oc] * (1.f / NPC) - mean * mean;
            const float rstd = rsqrtf(var + EPS);
            const float sc = gamma[oc] * rstd;
            const float sh = fmaf(-mean, sc, beta[oc]);
#pragma unroll
            for (int px = 0; px < TPX; ++px) {
                size_t oidx = (((size_t)(b * COUT + oc)) * HH + (h0 + px)) * WW + w;
                out[oidx] = fmaxf(fmaf(acc[px][oc], sc, sh), 0.f);
            }
        }
    }
}

// BN+ReLU from bf16 ws: 16 elements/thread, nontemporal in/out.
__global__ __launch_bounds__(256)
void bn_kernel(const unsigned short* __restrict__ ws_y,
               const float* __restrict__ stats,
               const float* __restrict__ gamma,
               const float* __restrict__ beta,
               float* __restrict__ out) {
    const size_t i16 = ((size_t)blockIdx.x * 256 + threadIdx.x) * 16;
    const int oc = (int)((i16 >> 18) & 7);  // HH*WW = 2^18
    const float mean = stats[oc] * (1.f / NPC);
    const float var  = stats[COUT + oc] * (1.f / NPC) - mean * mean;
    const float rstd = rsqrtf(var + EPS);
    const float sc = gamma[oc] * rstd;
    const float sh = fmaf(-mean, sc, beta[oc]);

    const uv4* src = (const uv4*)((const char*)ws_y + i16 * 2);
#pragma unroll
    for (int half = 0; half < 2; ++half) {
        const uv4 u = __builtin_nontemporal_load(src + half);
        float v[8];
        v[0] = __uint_as_float(u.x << 16);
        v[1] = __uint_as_float(u.x & 0xffff0000u);
        v[2] = __uint_as_float(u.y << 16);
        v[3] = __uint_as_float(u.y & 0xffff0000u);
        v[4] = __uint_as_float(u.z << 16);
        v[5] = __uint_as_float(u.z & 0xffff0000u);
        v[6] = __uint_as_float(u.w << 16);
        v[7] = __uint_as_float(u.w & 0xffff0000u);
        fv4 o0, o1;
        o0.x = fmaxf(fmaf(v[0], sc, sh), 0.f);
        o0.y = fmaxf(fmaf(v[1], sc, sh), 0.f);
        o0.z = fmaxf(fmaf(v[2], sc, sh), 0.f);
        o0.w = fmaxf(fmaf(v[3], sc, sh), 0.f);
        o1.x = fmaxf(fmaf(v[4], sc, sh), 0.f);
        o1.y = fmaxf(fmaf(v[5], sc, sh), 0.f);
        o1.z = fmaxf(fmaf(v[6], sc, sh), 0.f);
        o1.w = fmaxf(fmaf(v[7], sc, sh), 0.f);
        __builtin_nontemporal_store(o0, (fv4*)(out + i16 + half * 8));
        __builtin_nontemporal_store(o1, (fv4*)(out + i16 + half * 8 + 4));
    }
}

extern "C" void kernel_launch(void* const* d_in, const int* in_sizes, int n_in,
                              void* d_out, int out_size, void* d_ws, size_t ws_size,
                              hipStream_t stream) {
    const float* x     = (const float*)d_in[0];
    const float* lin_w = (const float*)d_in[1];
    // d_in[2] = lin_b: per-channel constant shift, cancelled exactly by BN -> unused.
    const float* gamma = (const float*)d_in[3];
    const float* beta  = (const float*)d_in[4];
    float* out = (float*)d_out;

    float* stats = (float*)d_ws;                                    // 16 floats
    unsigned short* ws_y = (unsigned short*)((char*)d_ws + 256);    // conv out, bf16 bits

    const size_t n_elem = (size_t)BATCH * COUT * HH * WW;           // 33,554,432
    const size_t need = 256 + n_elem * 2;

    (void)hipMemsetAsync(d_ws, 0, 256, stream);  // zero stats

    dim3 grid(WW / 256, HH / TPX, BATCH);
    if (ws_size >= need) {
        conv_kernel<0><<<grid, 256, 0, stream>>>(x, lin_w, gamma, beta, ws_y, stats, out);
        bn_kernel<<<(unsigned)(n_elem / (16 * 256)), 256, 0, stream>>>(ws_y, stats, gamma, beta, out);
    } else {
        conv_kernel<1><<<grid, 256, 0, stream>>>(x, lin_w, gamma, beta, ws_y, stats, out);
        conv_kernel<2><<<grid, 256, 0, stream>>>(x, lin_w, gamma, beta, ws_y, stats, out);
    }
}